// Round 16
// baseline (261.523 us; speedup 1.0000x reference)
//
#include <hip/hip_runtime.h>

// AdultConnectomeNetwork: 3 layers of xt = A_sp @ (W_sp @ xt) + bias.
// Round 16: 8 rows/wave + degree-sorted row scheduling.
//  - SpMM: lane l in 0..7 owns batch cols 4l..4l+3 as fp16x4 (uint2).
//    8 lanes/row -> 8 rows per wave64 (round 15: 4). Gathers stay one
//    64B line per row per instr; kv broadcasts serve 8 rows.
//  - Wave trip = max(niter) over its rows: E[max8 Poisson] ~ 6.2 vs mean
//    4.4 = 40% masked waste. pass2 counting-sorts each bin's 128 rows by
//    niter and emits sdesc/srow in sorted order -> waves get equal-length
//    rows, trip ~= mean. Wave-iters/pass: 69K -> ~28K.
//  - FMAs written as f32 += (f16)*(f16) to pattern-match v_fma_mix_f32.
//  - Rows padded to multiple-of-8 edges (zero kv = exact no-op), uniform
//    counted loop, uint2 kv loads, software pipeline (round 14).
//  - Scaled fp16 state: state_l = xt_l*256^-l (round 13; overflow-proof).
//  - Sort: two-pass LDS-staged counting sort (rounds 9-13).
// Hardening: computed indices clamped (logic error -> absmax fail, not fault).

#define NN 50000
#define NNZ_E 1600000
#define NB (NN * 32)
#define CHUNK 6144
#define NBLK1 ((NNZ_E + CHUNK - 1) / CHUNK)      // 261
#define NBIN ((NN + 127) / 128)                  // 391 bins of 128 rows
#define NH (NBIN * NBLK1)                        // 102051
#define CAP2 5120                                // bin window cap (mean 4092, +16 sigma)
#define BCAP 6144                                // padded per-bin capacity
#define LENP (NBIN * BCAP)                       // 2402304 padded slots
#define SCAN_NBLK ((NH + 255) / 256)             // 399

__device__ __forceinline__ int clampi(int v, int hi) {  // [0, hi]
    v = v < 0 ? 0 : v;
    return v > hi ? hi : v;
}

__device__ __forceinline__ unsigned short f2h(float v) {
    union { _Float16 h; unsigned short u; } cv;
    cv.h = (_Float16)v;
    return cv.u;
}

__device__ __forceinline__ _Float16 kv_val_h(unsigned kv) {
    union { unsigned short u; _Float16 h; } cv;
    cv.u = (unsigned short)(kv >> 16);
    return cv.h;
}

// Per-(chunk,bin) histogram matrix, bin-major. LDS only, no global atomics.
__global__ __launch_bounds__(256) void hist_kernel(const int* __restrict__ row,
                                                   int* __restrict__ hist1) {
    __shared__ int h[NBIN];
    int blk = blockIdx.x, tid = threadIdx.x;
    for (int j = tid; j < NBIN; j += 256) h[j] = 0;
    __syncthreads();
    int base = blk * CHUNK;
    int n = NNZ_E - base; if (n > CHUNK) n = CHUNK;
    for (int i = tid; i < n; i += 256)
        atomicAdd(&h[clampi(row[base + i], NN - 1) >> 7], 1);
    __syncthreads();
    for (int j = tid; j < NBIN; j += 256) hist1[j * NBLK1 + blk] = h[j];
}

// Exclusive scan within 256-blocks; bsum[blk] = block total.
__global__ void scan_local_kernel(int* __restrict__ data, int n, int* __restrict__ bsum) {
    __shared__ int s[256];
    int i = blockIdx.x * 256 + threadIdx.x;
    int v = (i < n) ? data[i] : 0;
    s[threadIdx.x] = v;
    __syncthreads();
    for (int off = 1; off < 256; off <<= 1) {
        int t = (threadIdx.x >= off) ? s[threadIdx.x - off] : 0;
        __syncthreads();
        s[threadIdx.x] += t;
        __syncthreads();
    }
    if (i < n) data[i] = s[threadIdx.x] - v;     // exclusive within block
    if (threadIdx.x == 255) bsum[blockIdx.x] = s[threadIdx.x];
}

// One block, 512 threads: exclusive scan of bsum[m], m <= 512 (m = 399).
__global__ void scan_tops_kernel(int* __restrict__ bsum, int m) {
    __shared__ int s[512];
    int t = threadIdx.x;
    int v = (t < m) ? bsum[t] : 0;
    s[t] = v;
    __syncthreads();
    for (int off = 1; off < 512; off <<= 1) {
        int u = (t >= off) ? s[t - off] : 0;
        __syncthreads();
        s[t] += u;
        __syncthreads();
    }
    if (t < m) bsum[t] = s[t] - v;               // exclusive
}

__global__ void fin_add_kernel(int* __restrict__ data, int n, const int* __restrict__ bsum) {
    int i = blockIdx.x * blockDim.x + threadIdx.x;
    if (i < n) data[i] += bsum[i >> 8];
}

// binstart[j] = scanned hist1[j*NBLK1].
__global__ void binstart_kernel(const int* __restrict__ hist1, int* __restrict__ binstart) {
    int j = blockIdx.x * blockDim.x + threadIdx.x;
    if (j < NBIN) binstart[j] = hist1[j * NBLK1];
    if (j == 0) binstart[NBIN] = NNZ_E;
}

// Pass 1: per-chunk in-LDS bin sort, payload staged as 8B/edge
// (key u32 + {fp16 a, fp16 w} u32); sequential reads, dense burst writes.
// key = (row<<16)|col (both < 2^16).
__global__ __launch_bounds__(256) void pass1_kernel(
        const int* __restrict__ row, const int* __restrict__ col,
        const float* __restrict__ a, const float* __restrict__ w,
        const int* __restrict__ hist1_off,
        unsigned* __restrict__ k1, unsigned* __restrict__ aw1) {
    __shared__ int h[NBIN];                  // counts -> placement cursors
    __shared__ int hscan[NBIN];              // block-local exclusive scan
    __shared__ int hoff[NBIN];               // global offsets for (bin, this blk)
    __shared__ int s256[256];
    __shared__ unsigned sKey[CHUNK];         // 24 KB
    __shared__ unsigned sAW[CHUNK];          // 24 KB
    int blk = blockIdx.x, tid = threadIdx.x;
    int base = blk * CHUNK;
    int n = NNZ_E - base; if (n > CHUNK) n = CHUNK;

    for (int j = tid; j < NBIN; j += 256) {
        h[j] = 0;
        hoff[j] = hist1_off[j * NBLK1 + blk];
    }
    __syncthreads();
    for (int i = tid; i < n; i += 256)
        atomicAdd(&h[clampi(row[base + i], NN - 1) >> 7], 1);
    __syncthreads();
    int j0 = tid * 2, j1 = tid * 2 + 1;
    int c0 = (j0 < NBIN) ? h[j0] : 0;
    int c1 = (j1 < NBIN) ? h[j1] : 0;
    int tsum = c0 + c1;
    s256[tid] = tsum;
    __syncthreads();
    for (int off = 1; off < 256; off <<= 1) {
        int t = (tid >= off) ? s256[tid - off] : 0;
        __syncthreads();
        s256[tid] += t;
        __syncthreads();
    }
    int ex = s256[tid] - tsum;
    __syncthreads();
    if (j0 < NBIN) { hscan[j0] = ex;      h[j0] = ex; }
    if (j1 < NBIN) { hscan[j1] = ex + c0; h[j1] = ex + c0; }
    __syncthreads();
    for (int i = tid; i < n; i += 256) {
        int r = clampi(row[base + i], NN - 1);
        int c = clampi(col[base + i], NN - 1);
        int bin = r >> 7;
        int p = atomicAdd(&h[bin], 1);       // LDS cursor, block-private
        p = clampi(p, n - 1);                // hardening
        sKey[p] = ((unsigned)r << 16) | (unsigned)c;
        sAW[p] = ((unsigned)f2h(a[base + i]) << 16) | (unsigned)f2h(w[base + i]);
    }
    __syncthreads();
    for (int p = tid; p < n; p += 256) {
        unsigned key = sKey[p];
        int bin = (int)(key >> 23);          // = row >> 7
        int d = clampi(hoff[bin] + (p - hscan[bin]), NNZ_E - 1);
        k1[d] = key;
        aw1[d] = sAW[p];
    }
}

// Pass 2: one block per 128-row bin. Row hist + padded-length scan in LDS;
// writes kvA2/kvW2 into the bin's fixed window (per-row multiple-of-8
// padding, pad kv=0); counting-sorts the bin's rows by niter and emits
// sdesc[slot] = window|niter<<24, srow[slot] = actual row, slot-major so
// each wave (8 consecutive slots) gets equal-length rows.
__global__ __launch_bounds__(256) void pass2_kernel(
        const unsigned* __restrict__ k1, const unsigned* __restrict__ aw1,
        const int* __restrict__ binstart,
        unsigned* __restrict__ kvA2, unsigned* __restrict__ kvW2,
        unsigned* __restrict__ sdesc, int* __restrict__ srow) {
    __shared__ unsigned sKey[CAP2];          // 20 KB
    __shared__ unsigned sAW[CAP2];           // 20 KB
    __shared__ int rh[128];
    __shared__ int rs[128];
    __shared__ int cur[128];
    __shared__ int rofsS[128];
    __shared__ int cnt64[64];
    int bin = blockIdx.x, tid = threadIdx.x;
    int r0 = bin << 7;
    int rows = NN - r0; if (rows > 128) rows = 128;
    int base = clampi(binstart[bin], NNZ_E);
    int size = clampi(binstart[bin + 1], NNZ_E) - base;
    size = clampi(size, CAP2);               // hardening (always fits in practice)
    int pbase = bin * BCAP;

    if (tid < 128) rh[tid] = 0;
    if (tid < 64) cnt64[tid] = 0;
    __syncthreads();
    for (int i = tid; i < size; i += 256) {
        unsigned key = k1[base + i];
        atomicAdd(&rh[(key >> 16) & 127], 1);
        sKey[i] = key;
        sAW[i] = aw1[base + i];
    }
    __syncthreads();
    int cnt  = (tid < 128) ? rh[tid] : 0;
    int plen = (cnt + 7) & ~7;
    if (tid < 128) rs[tid] = plen;
    __syncthreads();
    for (int off = 1; off < 128; off <<= 1) {
        int t = (tid >= off && tid < 128) ? rs[tid - off] : 0;
        __syncthreads();
        if (tid < 128) rs[tid] += t;
        __syncthreads();
    }
    int rofs = (tid < 128) ? clampi(rs[tid] - plen, BCAP - 8) : 0;
    if (tid < 128) { cur[tid] = rofs; rofsS[tid] = rofs; }
    // histogram of niter for the row-length counting sort
    int niter = plen >> 3;
    int skey = clampi(niter, 63);
    if (tid < rows) atomicAdd(&cnt64[skey], 1);
    __syncthreads();
    if (tid == 0) {                          // tiny serial scan of 64 bins
        int acc = 0;
        for (int q = 0; q < 64; ++q) { int v = cnt64[q]; cnt64[q] = acc; acc += v; }
    }
    __syncthreads();
    if (tid < rows) {
        int si = atomicAdd(&cnt64[skey], 1);
        si = clampi(si, rows - 1);           // hardening
        sdesc[r0 + si] = (unsigned)(pbase + rofs) | ((unsigned)niter << 24);
        srow[r0 + si]  = r0 + tid;
    }
    __syncthreads();
    // place edges (order within a row irrelevant)
    for (int i = tid; i < size; i += 256) {
        unsigned key = sKey[i];
        unsigned aw  = sAW[i];
        int rl = (key >> 16) & 127;
        int p = atomicAdd(&cur[rl], 1);
        p = clampi(p, BCAP - 1);             // hardening
        unsigned c = key & 0xFFFFu;
        kvA2[pbase + p] = (aw & 0xFFFF0000u) | c;
        kvW2[pbase + p] = (aw << 16) | c;
    }
    __syncthreads();
    // zero-fill pad slots (col=0, val=0 -> exact no-op in spmm)
    if (tid < rows) {
        int pl = (rh[tid] + 7) & ~7;
        for (int q = rh[tid]; q < pl; ++q) {
            int d = clampi(rofsS[tid] + q, BCAP - 1);
            kvA2[pbase + d] = 0u;
            kvW2[pbase + d] = 0u;
        }
    }
}

__global__ void transpose_in_kernel(const float* __restrict__ x,
                                    _Float16* __restrict__ xt) {
    int i = blockIdx.x * blockDim.x + threadIdx.x;  // i = n*32 + b
    if (i < NB) {
        int n = i >> 5;
        int b = i & 31;
        xt[i] = (_Float16)x[b * NN + n];
    }
}

// 8 lanes per row; lane l owns batch cols 4l..4l+3 as fp16x4 (uint2).
// 8 rows per wave64, rows degree-sorted so trip ~= mean niter. Uniform
// counted loop, uint2 kv loads, software-pipelined, fp32 accumulation via
// f32 += (f16)*(f16) (v_fma_mix), packed uint2 store.
template <int WITH_BIAS>
__global__ __launch_bounds__(256) void spmm_kernel(
        const uint2* __restrict__ kv2, const unsigned* __restrict__ sdesc,
        const int* __restrict__ srow,
        const uint2* __restrict__ in64, uint2* __restrict__ out64,
        const float* __restrict__ bias, float outScale, float biasScale) {
    int t = blockIdx.x * 256 + threadIdx.x;
    int g = t >> 3;                          // sorted slot: one row per 8 lanes
    int l = t & 7;                           // batch-quad index
    if (g >= NN) return;
    unsigned d = sdesc[g];
    int r = clampi(srow[g], NN - 1);
    int niter = (int)(d >> 24);
    int base2 = clampi((int)(d & 0xFFFFFFu), LENP - 8) >> 1;  // 8-slot aligned
    float a0 = 0.0f, a1 = 0.0f, a2 = 0.0f, a3 = 0.0f;
    uint2 k2[4];
    if (niter > 0) {
#pragma unroll
        for (int q = 0; q < 4; ++q) k2[q] = kv2[base2 + q];
    }
    for (int it = 0; it < niter; ++it) {
        unsigned k[8];
#pragma unroll
        for (int q = 0; q < 4; ++q) { k[2 * q] = k2[q].x; k[2 * q + 1] = k2[q].y; }
        uint2 gd[8];
#pragma unroll
        for (int j = 0; j < 8; ++j) gd[j] = in64[((k[j] & 0xFFFFu) << 3) + l];
        if (it + 1 < niter) {
            int nb2 = base2 + (it + 1) * 4;
#pragma unroll
            for (int q = 0; q < 4; ++q) k2[q] = kv2[nb2 + q];
        }
#pragma unroll
        for (int j = 0; j < 8; ++j) {
            _Float16 vh = kv_val_h(k[j]);
            union { uint2 u; _Float16 h[4]; } cv;
            cv.u = gd[j];
            a0 += (float)vh * (float)cv.h[0];
            a1 += (float)vh * (float)cv.h[1];
            a2 += (float)vh * (float)cv.h[2];
            a3 += (float)vh * (float)cv.h[3];
        }
    }
    float r0 = a0 * outScale, r1 = a1 * outScale;
    float r2 = a2 * outScale, r3 = a3 * outScale;
    if (WITH_BIAS) {
        float bb = bias[r] * biasScale;
        r0 += bb; r1 += bb; r2 += bb; r3 += bb;
    }
    union { uint2 u; _Float16 h[4]; } o;
    o.h[0] = (_Float16)r0; o.h[1] = (_Float16)r1;
    o.h[2] = (_Float16)r2; o.h[3] = (_Float16)r3;
    out64[(r << 3) + l] = o.u;
}

// Final: out = state * 2^24 (undoes the cumulative 256^-3 state scaling).
__global__ void transpose_out_kernel(const _Float16* __restrict__ xt,
                                     float* __restrict__ out) {
    int i = blockIdx.x * blockDim.x + threadIdx.x;  // i = b*N + n (coalesced write)
    if (i < NB) {
        int b = i / NN;
        int n = i - b * NN;
        out[i] = (float)xt[(n << 5) + b] * 16777216.0f;
    }
}

extern "C" void kernel_launch(void* const* d_in, const int* in_sizes, int n_in,
                              void* d_out, int out_size, void* d_ws, size_t ws_size,
                              hipStream_t stream) {
    const float* x        = (const float*)d_in[0];
    const float* adj_vals = (const float*)d_in[1];
    const float* w_vals   = (const float*)d_in[2];
    const float* bias     = (const float*)d_in[3];
    const int*   row      = (const int*)d_in[4];
    const int*   col      = (const int*)d_in[5];
    float* out = (float*)d_out;

    // Workspace (~41 MB of the 256 MiB ws)
    unsigned*  k1        = (unsigned*)d_ws;          // NNZ_E (sort keys)
    unsigned*  aw1       = k1 + NNZ_E;               // NNZ_E (packed fp16 a,w)
    unsigned*  kvA2      = aw1 + NNZ_E;              // LENP padded kv (A)
    unsigned*  kvW2      = kvA2 + LENP;              // LENP padded kv (W)
    _Float16*  xt16      = (_Float16*)(kvW2 + LENP); // NB fp16
    _Float16*  tmp16     = xt16 + NB;                // NB fp16
    int*   hist1         = (int*)(tmp16 + NB);       // NH (scanned in place)
    int*   bsumB         = hist1 + NH;               // 512
    int*   binstart      = bsumB + 512;              // NBIN+1 (+pad)
    unsigned* sdesc      = (unsigned*)(binstart + NBIN + 8);  // NN
    int*      srow       = (int*)(sdesc + NN + 8);            // NN

    const int BS = 256;
    const int grid_nb   = (NB + BS - 1) / BS;        // 6250
    const int grid_spmm = (NN * 8 + BS - 1) / BS;    // 1563

    // ---- (chunk,bin) histogram matrix + bin-major scan ----
    hist_kernel<<<NBLK1, BS, 0, stream>>>(row, hist1);
    scan_local_kernel<<<SCAN_NBLK, BS, 0, stream>>>(hist1, NH, bsumB);
    scan_tops_kernel<<<1, 512, 0, stream>>>(bsumB, SCAN_NBLK);
    fin_add_kernel<<<SCAN_NBLK, BS, 0, stream>>>(hist1, NH, bsumB);
    binstart_kernel<<<(NBIN + 1 + BS - 1) / BS, BS, 0, stream>>>(hist1, binstart);

    // ---- two-pass sort: bin-group then padded, degree-sorted placement ----
    pass1_kernel<<<NBLK1, BS, 0, stream>>>(row, col, adj_vals, w_vals,
                                           hist1, k1, aw1);
    pass2_kernel<<<NBIN, BS, 0, stream>>>(k1, aw1, binstart, kvA2, kvW2,
                                          sdesc, srow);

    const uint2* kvA = (const uint2*)kvA2;
    const uint2* kvW = (const uint2*)kvW2;
    const uint2* xtg  = (const uint2*)xt16;
    uint2*       xtgw = (uint2*)xt16;
    const uint2* tmg  = (const uint2*)tmp16;
    uint2*       tmgw = (uint2*)tmp16;

    // ---- dense passes (scaled fp16 state: state_l = xt_l * 256^-l) ----
    transpose_in_kernel<<<grid_nb, BS, 0, stream>>>(x, xt16);
    const float r256 = 1.0f / 256.0f;
    float biasScale = 1.0f;
    for (int layer = 0; layer < 3; ++layer) {
        biasScale *= r256;                   // 256^-(layer+1)
        spmm_kernel<0><<<grid_spmm, BS, 0, stream>>>(kvW, sdesc, srow, xtg, tmgw,
                                                     nullptr, 1.0f, 0.0f);
        spmm_kernel<1><<<grid_spmm, BS, 0, stream>>>(kvA, sdesc, srow, tmg, xtgw,
                                                     bias, r256, biasScale);
    }
    transpose_out_kernel<<<grid_nb, BS, 0, stream>>>(xt16, out);
}